// Round 1
// baseline (472.828 us; speedup 1.0000x reference)
//
#include <hip/hip_runtime.h>
#include <cstdint>
#include <cstddef>

typedef unsigned short u16;
typedef __bf16 bf16x8 __attribute__((ext_vector_type(8)));
typedef float f32x4 __attribute__((ext_vector_type(4)));

#define KOFF 27
#define EPSBN 1e-5f

__device__ inline u16 f2bf(float f) {
  unsigned int u = __float_as_uint(f);
  unsigned int r = (u + 0x7FFFu + ((u >> 16) & 1u)) >> 16;  // RNE
  return (u16)r;
}
__device__ inline float bf2f(u16 h) {
  return __uint_as_float(((unsigned int)h) << 16);
}

// ---------------- prep kernels ----------------

__global__ void k_prep_feats(const float* __restrict__ in, u16* __restrict__ out, int n4) {
  int i = blockIdx.x * 256 + threadIdx.x;
  if (i >= n4) return;
  const float4 v = reinterpret_cast<const float4*>(in)[i];
  ushort4 o;
  o.x = f2bf(v.x); o.y = f2bf(v.y); o.z = f2bf(v.z); o.w = f2bf(v.w);
  reinterpret_cast<ushort4*>(out)[i] = o;
}

// Pack W[k][j][c] (27x64x64 f32) into per-lane MFMA B-fragment order (bf16):
// Wp[ k*4096 + ks*2048 + ct*512 + lane*8 + e ] = W[k][ ks*32 + (lane>>4)*8 + e ][ ct*16 + (lane&15) ]
__global__ void k_prep_w(const float* __restrict__ W, u16* __restrict__ Wp) {
  int tid = blockIdx.x * 256 + threadIdx.x;
  if (tid >= KOFF * 4096) return;
  int k = tid >> 12;
  int rem = tid & 4095;
  int slot = rem >> 3;
  int e = rem & 7;
  int ks = slot >> 8;
  int ct = (slot >> 6) & 3;
  int lane = slot & 63;
  int j = ks * 32 + ((lane >> 4) << 3) + e;
  int c = ct * 16 + (lane & 15);
  Wp[tid] = f2bf(W[(k * 64 + j) * 64 + c]);
}

// Transpose nbr [N,27] -> nbrT [27,N] via LDS tiles (coalesced both sides)
__global__ void k_prep_nbrT(const int* __restrict__ nbr, int* __restrict__ nbrT, int N) {
  __shared__ int L[64 * KOFF];
  const int t = threadIdx.x;
  const int v0 = blockIdx.x * 64;
  const int nv = min(64, N - v0);
  const int cnt = nv * KOFF;
  for (int i = t; i < cnt; i += 256) L[i] = nbr[(size_t)v0 * KOFF + i];
  __syncthreads();
  for (int i = t; i < KOFF * 64; i += 256) {
    int k = i >> 6, j = i & 63;
    if (j < nv) nbrT[(size_t)k * N + v0 + j] = L[j * KOFF + k];
  }
}

// ---------------- conv kernel ----------------
// Block: 256 voxels x 64 channels. 4 waves, each 64 voxels x 64 ch.
// A tile in LDS: [256][64] bf16, 16B-chunk XOR swizzle (chunk ^= row&7).
// B tile in LDS: 8KB, pre-packed fragment order.
__launch_bounds__(256)
__global__ void k_conv(const u16* __restrict__ F, const u16* __restrict__ Wp,
                       const int* __restrict__ nbrT, float* __restrict__ out, int N) {
  __shared__ u16 A[256 * 64];   // 32 KB
  __shared__ u16 Bs[4096];      //  8 KB
  const int t = threadIdx.x;
  const int w = t >> 6;
  const int lane = t & 63;
  const int v0 = blockIdx.x << 8;

  f32x4 acc[4][4];
#pragma unroll
  for (int m = 0; m < 4; ++m)
#pragma unroll
    for (int c = 0; c < 4; ++c) acc[m][c] = (f32x4){0.f, 0.f, 0.f, 0.f};

  const int r_mine = t >> 2;  // 0..63 (row within 64-row pass)
  const int q_mine = t & 3;   // 16B chunk index (and +4)

  for (int k = 0; k < KOFF; ++k) {
    __syncthreads();  // previous iteration's LDS reads done
    // stage B (8KB): 2 x uint4 per thread
    {
      const uint4* src = reinterpret_cast<const uint4*>(Wp + ((size_t)k << 12));
      uint4* dst = reinterpret_cast<uint4*>(Bs);
      dst[t] = src[t];
      dst[t + 256] = src[t + 256];
    }
    // gather A: 4 passes x 64 rows, 4 threads/row (2 x 16B each)
    const int* nk = nbrT + (size_t)k * N;
#pragma unroll
    for (int p = 0; p < 4; ++p) {
      const int r = (p << 6) + r_mine;
      const int v = v0 + r;
      int id = (v < N) ? nk[v] : -1;
      uint4 d0 = {0u, 0u, 0u, 0u}, d1 = {0u, 0u, 0u, 0u};
      if (id >= 0) {
        const uint4* fr = reinterpret_cast<const uint4*>(F + ((size_t)id << 6));
        d0 = fr[q_mine];
        d1 = fr[q_mine + 4];
      }
      const int s = r & 7;
      uint4* arow = reinterpret_cast<uint4*>(A + (r << 6));
      arow[q_mine ^ s] = d0;
      arow[(q_mine + 4) ^ s] = d1;
    }
    __syncthreads();  // staging visible
    // compute: 2 K-subtiles x 4 m-tiles x 4 ct-tiles
#pragma unroll
    for (int ks = 0; ks < 2; ++ks) {
      bf16x8 af[4];
#pragma unroll
      for (int m = 0; m < 4; ++m) {
        const int row = (w << 6) + (m << 4) + (lane & 15);
        const int chunk = ((ks << 2) + (lane >> 4)) ^ (row & 7);
        af[m] = *reinterpret_cast<const bf16x8*>(A + (row << 6) + (chunk << 3));
      }
      bf16x8 bf[4];
#pragma unroll
      for (int c = 0; c < 4; ++c)
        bf[c] = *reinterpret_cast<const bf16x8*>(Bs + (ks << 11) + (c << 9) + (lane << 3));
#pragma unroll
      for (int m = 0; m < 4; ++m)
#pragma unroll
        for (int c = 0; c < 4; ++c)
          acc[m][c] = __builtin_amdgcn_mfma_f32_16x16x32_bf16(af[m], bf[c], acc[m][c], 0, 0, 0);
    }
  }
  // epilogue: C/D layout col=lane&15, row=(lane>>4)*4+e  [m89-verified]
#pragma unroll
  for (int m = 0; m < 4; ++m) {
    const int row0 = v0 + (w << 6) + (m << 4) + ((lane >> 4) << 2);
#pragma unroll
    for (int c = 0; c < 4; ++c) {
      const int col = (c << 4) + (lane & 15);
#pragma unroll
      for (int e = 0; e < 4; ++e) {
        const int v = row0 + e;
        if (v < N) out[((size_t)v << 6) + col] = acc[m][c][e];
      }
    }
  }
}

// ---------------- BN stats / apply ----------------

// 256 blocks x 256 threads. Thread: channel-group cg=t&15 (4 ch), row-lane rl=t>>4.
__global__ void k_stats(const float* __restrict__ x, float* __restrict__ partial, int N) {
  const int t = threadIdx.x;
  const int cg = t & 15;
  const int rl = t >> 4;
  float s0 = 0, s1 = 0, s2 = 0, s3 = 0, q0 = 0, q1 = 0, q2 = 0, q3 = 0;
  for (int r = blockIdx.x * 16 + rl; r < N; r += 4096) {
    const float4 v = reinterpret_cast<const float4*>(x)[(size_t)r * 16 + cg];
    s0 += v.x; s1 += v.y; s2 += v.z; s3 += v.w;
    q0 += v.x * v.x; q1 += v.y * v.y; q2 += v.z * v.z; q3 += v.w * v.w;
  }
  __shared__ float S[256][8];
  S[t][0] = s0; S[t][1] = s1; S[t][2] = s2; S[t][3] = s3;
  S[t][4] = q0; S[t][5] = q1; S[t][6] = q2; S[t][7] = q3;
  __syncthreads();
  for (int st = 8; st >= 1; st >>= 1) {
    if (rl < st) {
      const int o = t + st * 16;
#pragma unroll
      for (int j = 0; j < 8; ++j) S[t][j] += S[o][j];
    }
    __syncthreads();
  }
  if (rl == 0) {
    float4 ss = {S[t][0], S[t][1], S[t][2], S[t][3]};
    float4 qq = {S[t][4], S[t][5], S[t][6], S[t][7]};
    reinterpret_cast<float4*>(partial)[blockIdx.x * 32 + cg] = ss;
    reinterpret_cast<float4*>(partial)[blockIdx.x * 32 + 16 + cg] = qq;
  }
}

__global__ void k_final(const float* __restrict__ partial, const float* __restrict__ gamma,
                        const float* __restrict__ beta, float* __restrict__ sb, int N) {
  const int c = threadIdx.x;  // 64
  float s = 0, q = 0;
  for (int b = 0; b < 256; ++b) {
    s += partial[b * 128 + c];
    q += partial[b * 128 + 64 + c];
  }
  float inv = 1.0f / (float)N;
  float mu = s * inv;
  float var = q * inv - mu * mu;
  float sc = gamma[c] * rsqrtf(var + EPSBN);
  sb[c] = sc;
  sb[64 + c] = beta[c] - mu * sc;
}

// y = relu(x*sc+bi) -> bf16 x_net
__global__ void k_apply1(const float* __restrict__ x, const float* __restrict__ sb,
                         u16* __restrict__ xb, int n4) {
  int i = blockIdx.x * 256 + threadIdx.x;
  if (i >= n4) return;
  const int cg = i & 15;
  float4 v = reinterpret_cast<const float4*>(x)[i];
  const float4 sc = reinterpret_cast<const float4*>(sb)[cg];
  const float4 bi = reinterpret_cast<const float4*>(sb)[16 + cg];
  float y0 = fmaxf(0.f, v.x * sc.x + bi.x);
  float y1 = fmaxf(0.f, v.y * sc.y + bi.y);
  float y2 = fmaxf(0.f, v.z * sc.z + bi.z);
  float y3 = fmaxf(0.f, v.w * sc.w + bi.w);
  ushort4 o;
  o.x = f2bf(y0); o.y = f2bf(y1); o.z = f2bf(y2); o.w = f2bf(y3);
  reinterpret_cast<ushort4*>(xb)[i] = o;
}

// out = x_net + relu(x*sc+bi)   (in-place on conv2 raw output)
__global__ void k_apply2(float* __restrict__ io, const float* __restrict__ sb,
                         const u16* __restrict__ xb, int n4) {
  int i = blockIdx.x * 256 + threadIdx.x;
  if (i >= n4) return;
  const int cg = i & 15;
  float4 v = reinterpret_cast<const float4*>(io)[i];
  const float4 sc = reinterpret_cast<const float4*>(sb)[cg];
  const float4 bi = reinterpret_cast<const float4*>(sb)[16 + cg];
  const ushort4 xn = reinterpret_cast<const ushort4*>(xb)[i];
  float4 o;
  o.x = bf2f(xn.x) + fmaxf(0.f, v.x * sc.x + bi.x);
  o.y = bf2f(xn.y) + fmaxf(0.f, v.y * sc.y + bi.y);
  o.z = bf2f(xn.z) + fmaxf(0.f, v.z * sc.z + bi.z);
  o.w = bf2f(xn.w) + fmaxf(0.f, v.w * sc.w + bi.w);
  reinterpret_cast<float4*>(io)[i] = o;
}

// ---------------- host ----------------

extern "C" void kernel_launch(void* const* d_in, const int* in_sizes, int n_in,
                              void* d_out, int out_size, void* d_ws, size_t ws_size,
                              hipStream_t stream) {
  const float* feats = (const float*)d_in[0];
  const float* W1 = (const float*)d_in[1];
  const float* g1 = (const float*)d_in[2];
  const float* b1 = (const float*)d_in[3];
  const float* W2 = (const float*)d_in[4];
  const float* g2 = (const float*)d_in[5];
  const float* b2 = (const float*)d_in[6];
  const int* nbr = (const int*)d_in[7];
  const int N = in_sizes[0] / 64;

  char* ws = (char*)d_ws;
  size_t off = 0;
  auto alloc = [&](size_t bytes) {
    void* p = ws + off;
    off = (off + bytes + 255) & ~(size_t)255;
    return p;
  };
  u16* featsb = (u16*)alloc((size_t)N * 64 * 2);
  u16* xnetb = (u16*)alloc((size_t)N * 64 * 2);
  u16* w1p = (u16*)alloc((size_t)KOFF * 4096 * 2);
  u16* w2p = (u16*)alloc((size_t)KOFF * 4096 * 2);
  float* partial = (float*)alloc((size_t)256 * 128 * 4);
  float* sb = (float*)alloc(128 * 4);
  int* nbrT = (int*)alloc((size_t)KOFF * N * 4);
  float* outf = (float*)d_out;

  const int n4 = N * 16;
  const int gApply = (n4 + 255) / 256;
  const int gW = (KOFF * 4096 + 255) / 256;
  const int gConv = (N + 255) / 256;

  k_prep_feats<<<gApply, 256, 0, stream>>>(feats, featsb, n4);
  k_prep_w<<<gW, 256, 0, stream>>>(W1, w1p);
  k_prep_w<<<gW, 256, 0, stream>>>(W2, w2p);
  k_prep_nbrT<<<(N + 63) / 64, 256, 0, stream>>>(nbr, nbrT, N);

  k_conv<<<gConv, 256, 0, stream>>>(featsb, w1p, nbrT, outf, N);
  k_stats<<<256, 256, 0, stream>>>(outf, partial, N);
  k_final<<<1, 64, 0, stream>>>(partial, g1, b1, sb, N);
  k_apply1<<<gApply, 256, 0, stream>>>(outf, sb, xnetb, n4);

  k_conv<<<gConv, 256, 0, stream>>>(xnetb, w2p, nbrT, outf, N);
  k_stats<<<256, 256, 0, stream>>>(outf, partial, N);
  k_final<<<1, 64, 0, stream>>>(partial, g2, b2, sb, N);
  k_apply2<<<gApply, 256, 0, stream>>>(outf, sb, xnetb, n4);
}

// Round 2
// 267.359 us; speedup vs baseline: 1.7685x; 1.7685x over previous
//
#include <hip/hip_runtime.h>
#include <cstdint>
#include <cstddef>

typedef unsigned short u16;
typedef __bf16 bf16x8 __attribute__((ext_vector_type(8)));
typedef float f32x4 __attribute__((ext_vector_type(4)));

#define KOFF 27
#define EPSBN 1e-5f

__device__ inline u16 f2bf(float f) {
  unsigned int u = __float_as_uint(f);
  unsigned int r = (u + 0x7FFFu + ((u >> 16) & 1u)) >> 16;  // RNE
  return (u16)r;
}
__device__ inline float bf2f(u16 h) {
  return __uint_as_float(((unsigned int)h) << 16);
}

// ---------------- prep kernels ----------------

// cast feats -> bf16; block 0 also zeroes the 256-float stats accumulators
__global__ void k_prep_feats(const float* __restrict__ in, u16* __restrict__ out,
                             float* __restrict__ stats, int n4) {
  if (blockIdx.x == 0) stats[threadIdx.x] = 0.f;
  int i = blockIdx.x * 256 + threadIdx.x;
  if (i >= n4) return;
  const float4 v = reinterpret_cast<const float4*>(in)[i];
  ushort4 o;
  o.x = f2bf(v.x); o.y = f2bf(v.y); o.z = f2bf(v.z); o.w = f2bf(v.w);
  reinterpret_cast<ushort4*>(out)[i] = o;
}

// Pack W[k][j][c] (27x64x64 f32) into per-lane MFMA B-fragment order (bf16):
// Wp[ k*4096 + ks*2048 + ct*512 + lane*8 + e ] = W[k][ ks*32 + (lane>>4)*8 + e ][ ct*16 + (lane&15) ]
__global__ void k_prep_w(const float* __restrict__ W, u16* __restrict__ Wp) {
  int tid = blockIdx.x * 256 + threadIdx.x;
  if (tid >= KOFF * 4096) return;
  int k = tid >> 12;
  int rem = tid & 4095;
  int slot = rem >> 3;
  int e = rem & 7;
  int ks = slot >> 8;
  int ct = (slot >> 6) & 3;
  int lane = slot & 63;
  int j = ks * 32 + ((lane >> 4) << 3) + e;
  int c = ct * 16 + (lane & 15);
  Wp[tid] = f2bf(W[(k * 64 + j) * 64 + c]);
}

// Transpose nbr [N,27] -> nbrT [27,N] via LDS tiles (coalesced both sides)
__global__ void k_prep_nbrT(const int* __restrict__ nbr, int* __restrict__ nbrT, int N) {
  __shared__ int L[64 * KOFF];
  const int t = threadIdx.x;
  const int v0 = blockIdx.x * 64;
  const int nv = min(64, N - v0);
  const int cnt = nv * KOFF;
  for (int i = t; i < cnt; i += 256) L[i] = nbr[(size_t)v0 * KOFF + i];
  __syncthreads();
  for (int i = t; i < KOFF * 64; i += 256) {
    int k = i >> 6, j = i & 63;
    if (j < nv) nbrT[(size_t)k * N + v0 + j] = L[j * KOFF + k];
  }
}

// ---------------- conv kernel (no LDS main loop, no barriers) ----------------
// Block 256 = 4 waves; each wave owns 64 voxels x all 64 output channels.
// A-fragments gathered straight from global (16B/lane, frag-layout-native);
// B-fragments read straight from global (pre-packed, L1/L2-resident).
// Neighbor indices for k+1 prefetched before the MFMA block.
// Epilogue fuses the BN batch-stat partial reduction (atomicAdd into stats[128]).
__launch_bounds__(256, 3)
__global__ void k_conv(const u16* __restrict__ F, const u16* __restrict__ Wp,
                       const int* __restrict__ nbrT, float* __restrict__ out,
                       float* __restrict__ stats, int N) {
  const int t = threadIdx.x;
  const int w = t >> 6;
  const int lane = t & 63;
  const int vbase = blockIdx.x * 256 + (w << 6) + (lane & 15);
  const int ch = (lane >> 4) << 3;  // A-frag channel offset (elements)

  f32x4 acc[4][4];
#pragma unroll
  for (int m = 0; m < 4; ++m)
#pragma unroll
    for (int c = 0; c < 4; ++c) acc[m][c] = (f32x4){0.f, 0.f, 0.f, 0.f};

  // prefetch k=0 neighbor indices
  int nid[4];
#pragma unroll
  for (int m = 0; m < 4; ++m) {
    const int v = vbase + (m << 4);
    nid[m] = (v < N) ? nbrT[v] : -1;
  }

  const u16* bp = Wp + ((size_t)lane << 3);

#pragma unroll 3
  for (int k = 0; k < KOFF; ++k) {
    // B fragments for this k (broadcast across waves -> L1/L2 hits)
    bf16x8 bfr[2][4];
#pragma unroll
    for (int ks = 0; ks < 2; ++ks)
#pragma unroll
      for (int c = 0; c < 4; ++c)
        bfr[ks][c] = *reinterpret_cast<const bf16x8*>(bp + ((size_t)k << 12) + (ks << 11) + (c << 9));

    // A fragments: direct register gather
    bf16x8 a0[4], a1[4];
#pragma unroll
    for (int m = 0; m < 4; ++m) {
      a0[m] = (bf16x8){};
      a1[m] = (bf16x8){};
      const int id = nid[m];
      if (id >= 0) {
        const u16* fr = F + ((size_t)id << 6) + ch;
        a0[m] = *reinterpret_cast<const bf16x8*>(fr);
        a1[m] = *reinterpret_cast<const bf16x8*>(fr + 32);
      }
    }

    // prefetch next k's indices (latency hidden under the MFMA block)
    if (k + 1 < KOFF) {
      const int* nk = nbrT + (size_t)(k + 1) * N;
#pragma unroll
      for (int m = 0; m < 4; ++m) {
        const int v = vbase + (m << 4);
        nid[m] = (v < N) ? nk[v] : -1;
      }
    }

#pragma unroll
    for (int m = 0; m < 4; ++m)
#pragma unroll
      for (int c = 0; c < 4; ++c)
        acc[m][c] = __builtin_amdgcn_mfma_f32_16x16x32_bf16(a0[m], bfr[0][c], acc[m][c], 0, 0, 0);
#pragma unroll
    for (int m = 0; m < 4; ++m)
#pragma unroll
      for (int c = 0; c < 4; ++c)
        acc[m][c] = __builtin_amdgcn_mfma_f32_16x16x32_bf16(a1[m], bfr[1][c], acc[m][c], 0, 0, 0);
  }

  // ---- store + fused BN-stat partial reduction ----
  const int row0 = blockIdx.x * 256 + (w << 6) + ((lane >> 4) << 2);
#pragma unroll
  for (int m = 0; m < 4; ++m) {
#pragma unroll
    for (int c = 0; c < 4; ++c) {
      const int col = (c << 4) + (lane & 15);
#pragma unroll
      for (int e = 0; e < 4; ++e) {
        const int v = row0 + (m << 4) + e;
        if (v < N) out[((size_t)v << 6) + col] = acc[m][c][e];
      }
    }
  }

  __shared__ float sred[4][128];
#pragma unroll
  for (int c = 0; c < 4; ++c) {
    float s = 0.f, q = 0.f;
#pragma unroll
    for (int m = 0; m < 4; ++m)
#pragma unroll
      for (int e = 0; e < 4; ++e) {
        const float x = acc[m][c][e];  // OOB rows contribute exact 0
        s += x;
        q += x * x;
      }
    s += __shfl_xor(s, 16, 64);
    s += __shfl_xor(s, 32, 64);
    q += __shfl_xor(q, 16, 64);
    q += __shfl_xor(q, 32, 64);
    if (lane < 16) {
      sred[w][(c << 4) + lane] = s;
      sred[w][64 + (c << 4) + lane] = q;
    }
  }
  __syncthreads();
  if (t < 128) {
    const float tot = sred[0][t] + sred[1][t] + sred[2][t] + sred[3][t];
    atomicAdd(&stats[t], tot);
  }
}

// ---------------- BN finalize / apply ----------------

__global__ void k_final(const float* __restrict__ stats, const float* __restrict__ gamma,
                        const float* __restrict__ beta, float* __restrict__ sb, int N) {
  const int c = threadIdx.x;  // 64
  const float inv = 1.0f / (float)N;
  const float mu = stats[c] * inv;
  const float var = stats[64 + c] * inv - mu * mu;
  const float sc = gamma[c] * rsqrtf(var + EPSBN);
  sb[c] = sc;
  sb[64 + c] = beta[c] - mu * sc;
}

// y = relu(x*sc+bi) -> bf16 x_net
__global__ void k_apply1(const float* __restrict__ x, const float* __restrict__ sb,
                         u16* __restrict__ xb, int n4) {
  int i = blockIdx.x * 256 + threadIdx.x;
  if (i >= n4) return;
  const int cg = i & 15;
  float4 v = reinterpret_cast<const float4*>(x)[i];
  const float4 sc = reinterpret_cast<const float4*>(sb)[cg];
  const float4 bi = reinterpret_cast<const float4*>(sb)[16 + cg];
  float y0 = fmaxf(0.f, v.x * sc.x + bi.x);
  float y1 = fmaxf(0.f, v.y * sc.y + bi.y);
  float y2 = fmaxf(0.f, v.z * sc.z + bi.z);
  float y3 = fmaxf(0.f, v.w * sc.w + bi.w);
  ushort4 o;
  o.x = f2bf(y0); o.y = f2bf(y1); o.z = f2bf(y2); o.w = f2bf(y3);
  reinterpret_cast<ushort4*>(xb)[i] = o;
}

// out = x_net + relu(x*sc+bi)   (in-place on conv2 raw output)
__global__ void k_apply2(float* __restrict__ io, const float* __restrict__ sb,
                         const u16* __restrict__ xb, int n4) {
  int i = blockIdx.x * 256 + threadIdx.x;
  if (i >= n4) return;
  const int cg = i & 15;
  float4 v = reinterpret_cast<const float4*>(io)[i];
  const float4 sc = reinterpret_cast<const float4*>(sb)[cg];
  const float4 bi = reinterpret_cast<const float4*>(sb)[16 + cg];
  const ushort4 xn = reinterpret_cast<const ushort4*>(xb)[i];
  float4 o;
  o.x = bf2f(xn.x) + fmaxf(0.f, v.x * sc.x + bi.x);
  o.y = bf2f(xn.y) + fmaxf(0.f, v.y * sc.y + bi.y);
  o.z = bf2f(xn.z) + fmaxf(0.f, v.z * sc.z + bi.z);
  o.w = bf2f(xn.w) + fmaxf(0.f, v.w * sc.w + bi.w);
  reinterpret_cast<float4*>(io)[i] = o;
}

// ---------------- host ----------------

extern "C" void kernel_launch(void* const* d_in, const int* in_sizes, int n_in,
                              void* d_out, int out_size, void* d_ws, size_t ws_size,
                              hipStream_t stream) {
  const float* feats = (const float*)d_in[0];
  const float* W1 = (const float*)d_in[1];
  const float* g1 = (const float*)d_in[2];
  const float* b1 = (const float*)d_in[3];
  const float* W2 = (const float*)d_in[4];
  const float* g2 = (const float*)d_in[5];
  const float* b2 = (const float*)d_in[6];
  const int* nbr = (const int*)d_in[7];
  const int N = in_sizes[0] / 64;

  char* ws = (char*)d_ws;
  size_t off = 0;
  auto alloc = [&](size_t bytes) {
    void* p = ws + off;
    off = (off + bytes + 255) & ~(size_t)255;
    return p;
  };
  u16* featsb = (u16*)alloc((size_t)N * 64 * 2);
  u16* xnetb = (u16*)alloc((size_t)N * 64 * 2);
  u16* w1p = (u16*)alloc((size_t)KOFF * 4096 * 2);
  u16* w2p = (u16*)alloc((size_t)KOFF * 4096 * 2);
  float* stats = (float*)alloc(256 * 4);   // [s1(64) q1(64) s2(64) q2(64)]
  float* sb1 = (float*)alloc(128 * 4);
  float* sb2 = (float*)alloc(128 * 4);
  int* nbrT = (int*)alloc((size_t)KOFF * N * 4);
  float* outf = (float*)d_out;

  const int n4 = N * 16;
  const int gApply = (n4 + 255) / 256;
  const int gW = (KOFF * 4096 + 255) / 256;
  const int gConv = (N + 255) / 256;

  k_prep_feats<<<gApply, 256, 0, stream>>>(feats, featsb, stats, n4);
  k_prep_w<<<gW, 256, 0, stream>>>(W1, w1p);
  k_prep_w<<<gW, 256, 0, stream>>>(W2, w2p);
  k_prep_nbrT<<<(N + 63) / 64, 256, 0, stream>>>(nbr, nbrT, N);

  k_conv<<<gConv, 256, 0, stream>>>(featsb, w1p, nbrT, outf, stats, N);
  k_final<<<1, 64, 0, stream>>>(stats, g1, b1, sb1, N);
  k_apply1<<<gApply, 256, 0, stream>>>(outf, sb1, xnetb, n4);

  k_conv<<<gConv, 256, 0, stream>>>(xnetb, w2p, nbrT, outf, stats + 128, N);
  k_final<<<1, 64, 0, stream>>>(stats + 128, g2, b2, sb2, N);
  k_apply2<<<gApply, 256, 0, stream>>>(outf, sb2, xnetb, n4);
}